// Round 1
// baseline (482.081 us; speedup 1.0000x reference)
//
#include <hip/hip_runtime.h>
#include <hip/hip_bf16.h>
#include <cstdint>

#define DEVINL __device__ __forceinline__

namespace {
constexpr int B = 4, T = 256, U = 101, V = 1024;
constexpr int BLANK = 1023;
constexpr float SIGMA = 0.05f;
constexpr float NEG_INF = -1.0e30f;
constexpr int TU = T * U;
constexpr int BTU = B * TU;
}

DEVINL float lae(float a, float b) {
  float m = fmaxf(a, b);
  float z = __expf(fminf(a, b) - m);   // exp(-huge) -> 0, safe
  return m + __logf(1.0f + z);
}

// ---------------- K1: per-(b,t,u) row reduction ----------------
// one wave (64 lanes) per row of 1029 floats. Emits compact DP operands.
__global__ void __launch_bounds__(256) k_prep(
    const float* __restrict__ acts, const int* __restrict__ labels,
    float* __restrict__ e0, float* __restrict__ stay, float* __restrict__ move) {
  int gwave = (blockIdx.x * 256 + threadIdx.x) >> 6;
  int lane = threadIdx.x & 63;
  if (gwave >= BTU) return;
  int b = gwave / TU;
  int rem = gwave - b * TU;
  int u = rem % U;
  const float* row = acts + (size_t)gwave * (V + 5);

  float x[16];
#pragma unroll
  for (int k = 0; k < 16; ++k) x[k] = row[k * 64 + lane];  // coalesced dword loads
  float m = x[0];
#pragma unroll
  for (int k = 1; k < 16; ++k) m = fmaxf(m, x[k]);
#pragma unroll
  for (int off = 32; off >= 1; off >>= 1) m = fmaxf(m, __shfl_xor(m, off, 64));
  float s = 0.f;
#pragma unroll
  for (int k = 0; k < 16; ++k) s += __expf(x[k] - m);
#pragma unroll
  for (int off = 32; off >= 1; off >>= 1) s += __shfl_xor(s, off, 64);
  float lse = m + __logf(s);

  if (lane == 0) {
    float blank = row[BLANK];
    int lab = (u < U - 1) ? labels[b * (U - 1) + u] : 0;
    float y = row[lab];
    float d0 = row[V + 0], d1 = row[V + 1], d2 = row[V + 2], d3 = row[V + 3], d4 = row[V + 4];
    float dm = fmaxf(fmaxf(fmaxf(d0, d1), fmaxf(d2, d3)), d4);
    float dl = dm + __logf(__expf(d0 - dm) + __expf(d1 - dm) + __expf(d2 - dm) +
                           __expf(d3 - dm) + __expf(d4 - dm));
    float bl = blank - lse - SIGMA;  // blank_lp
    float yl = y - lse - SIGMA;      // y_lp
    e0[gwave] = yl + (d0 - dl);
    float dd1 = d1 - dl, dd2 = d2 - dl, dd3 = d3 - dl, dd4 = d4 - dl;
    stay[0 * BTU + gwave] = bl + dd1;
    stay[1 * BTU + gwave] = bl + dd2;
    stay[2 * BTU + gwave] = bl + dd3;
    stay[3 * BTU + gwave] = bl + dd4;
    move[0 * BTU + gwave] = yl + dd1;
    move[1 * BTU + gwave] = yl + dd2;
    move[2 * BTU + gwave] = yl + dd3;
    move[3 * BTU + gwave] = yl + dd4;
  }
}

// ---------------- K2: forward DP, 1 block per batch ----------------
__global__ void __launch_bounds__(128) k_dp(
    const float* __restrict__ e0, const float* __restrict__ stay,
    const float* __restrict__ move, const int* __restrict__ act_lens,
    const int* __restrict__ label_lens, float* __restrict__ partial) {
  const int b = blockIdx.x;
  const int u = threadIdx.x;  // 0..127, active u < U
  const int lane = u & 63;
  const int wave = u >> 6;
  const bool active = (u < U);
  __shared__ float shA, shC;
  __shared__ float shTerm[4];
  const float* e0b = e0 + b * TU;
  const float* S1 = stay + 0 * BTU + b * TU;
  const float* S2 = stay + 1 * BTU + b * TU;
  const float* S3 = stay + 2 * BTU + b * TU;
  const float* S4 = stay + 3 * BTU + b * TU;
  const float* M1 = move + 0 * BTU + b * TU;
  const float* M2 = move + 1 * BTU + b * TU;
  const float* M3 = move + 2 * BTU + b * TU;
  const float* M4 = move + 3 * BTU + b * TU;
  const int al = act_lens[b];
  const int ll = label_lens[b];
  if (u == 0) { shTerm[0] = shTerm[1] = shTerm[2] = shTerm[3] = NEG_INF; }

  // alpha[t-d][u] and alpha[t-d][u-1] register rings
  float a1 = NEG_INF, a2 = NEG_INF, a3 = NEG_INF, a4 = NEG_INF;
  float am1 = NEG_INF, am2 = NEG_INF, am3 = NEG_INF, am4 = NEG_INF;
  // current-step operands (prefetched)
  float cs1 = 0, cs2 = 0, cs3 = 0, cs4 = 0, cm1 = 0, cm2 = 0, cm3 = 0, cm4 = 0, ce0 = 0;
  if (active && u >= 1) ce0 = e0b[u - 1];  // e0 row for t=0 scan
  __syncthreads();

  for (int t = 0; t < T; ++t) {
    // prefetch operands for t+1 (independent of this step's compute)
    float ns1 = 0, ns2 = 0, ns3 = 0, ns4 = 0, nm1 = 0, nm2 = 0, nm3 = 0, nm4 = 0, ne0 = 0;
    if (t + 1 < T && active) {
      const int tn = t + 1;
      if (u >= 1) ne0 = e0b[tn * U + u - 1];
      if (tn >= 1) ns1 = S1[(tn - 1) * U + u];
      if (tn >= 2) ns2 = S2[(tn - 2) * U + u];
      if (tn >= 3) ns3 = S3[(tn - 3) * U + u];
      if (tn >= 4) ns4 = S4[(tn - 4) * U + u];
      if (u >= 1) {
        if (tn >= 1) nm1 = M1[(tn - 1) * U + u - 1];
        if (tn >= 2) nm2 = M2[(tn - 2) * U + u - 1];
        if (tn >= 3) nm3 = M3[(tn - 3) * U + u - 1];
        if (tn >= 4) nm4 = M4[(tn - 4) * U + u - 1];
      }
    }

    // c[u]: positive-duration arrivals (+ init at (0,0))
    float c = (t == 0 && u == 0) ? 0.f : NEG_INF;
    if (t >= 1) { float st = a1 + cs1; float mv = (u >= 1) ? am1 + cm1 : NEG_INF; c = lae(c, lae(st, mv)); }
    if (t >= 2) { float st = a2 + cs2; float mv = (u >= 1) ? am2 + cm2 : NEG_INF; c = lae(c, lae(st, mv)); }
    if (t >= 3) { float st = a3 + cs3; float mv = (u >= 1) ? am3 + cm3 : NEG_INF; c = lae(c, lae(st, mv)); }
    if (t >= 4) { float st = a4 + cs4; float mv = (u >= 1) ? am4 + cm4 : NEG_INF; c = lae(c, lae(st, mv)); }

    // inclusive pair scan along u: r[u] = lae(r[u-1] + e0[t][u-1], c[u])
    float A = (active && u >= 1) ? ce0 : 0.f;  // identity element: (0, NEG_INF)
    float C = active ? c : NEG_INF;
#pragma unroll
    for (int off = 1; off < 64; off <<= 1) {
      float pA = __shfl_up(A, off, 64);
      float pC = __shfl_up(C, off, 64);
      if (lane >= off) { C = lae(pC + A, C); A = pA + A; }
    }
    if (u == 63) { shA = A; shC = C; }  // wave0 aggregate
    __syncthreads();
    if (wave == 1) { C = lae(shC + A, C); }
    float r = C;  // alpha[t][u]

    // final-term capture: alphas[tt,ll] + blank_lp + dlp_d == alphas[tt,ll] + stay_d[tt,ll]
    if (active && u == ll) {
      if (t == al - 1) shTerm[0] = r + S1[t * U + u];
      if (t == al - 2) shTerm[1] = r + S2[t * U + u];
      if (t == al - 3) shTerm[2] = r + S3[t * U + u];
      if (t == al - 4) shTerm[3] = r + S4[t * U + u];
    }

    // neighbor alpha[t][u-1]
    float rm = __shfl_up(r, 1, 64);
    if (u == 64) rm = shC;  // cross-wave seam: wave0's r[63]

    // shift rings
    a4 = a3; a3 = a2; a2 = a1; a1 = r;
    am4 = am3; am3 = am2; am2 = am1; am1 = rm;
    cs1 = ns1; cs2 = ns2; cs3 = ns3; cs4 = ns4;
    cm1 = nm1; cm2 = nm2; cm3 = nm3; cm4 = nm4;
    ce0 = ne0;
    __syncthreads();
  }

  if (u == 0) {
    float l1 = lae(lae(shTerm[0], shTerm[1]), lae(shTerm[2], shTerm[3]));
    partial[b] = -l1;
  }
}

// ---------------- K3: batch reduce ----------------
__global__ void k_final(const float* __restrict__ partial, float* __restrict__ out) {
  if (threadIdx.x == 0 && blockIdx.x == 0)
    out[0] = (partial[0] + partial[1] + partial[2] + partial[3]) * 0.25f;
}

extern "C" void kernel_launch(void* const* d_in, const int* in_sizes, int n_in,
                              void* d_out, int out_size, void* d_ws, size_t ws_size,
                              hipStream_t stream) {
  const float* acts = (const float*)d_in[0];
  const int* labels = (const int*)d_in[1];
  const int* act_lens = (const int*)d_in[2];
  const int* label_lens = (const int*)d_in[3];
  float* ws = (float*)d_ws;
  float* e0 = ws;                 // [B][T][U]
  float* stay = ws + BTU;         // [4][B][T][U]
  float* move = ws + 5 * BTU;     // [4][B][T][U]
  float* partial = ws + 9 * BTU;  // [B]
  float* out = (float*)d_out;

  k_prep<<<BTU / 4, 256, 0, stream>>>(acts, labels, e0, stay, move);
  k_dp<<<B, 128, 0, stream>>>(e0, stay, move, act_lens, label_lens, partial);
  k_final<<<1, 64, 0, stream>>>(partial, out);
}

// Round 3
// 265.728 us; speedup vs baseline: 1.8142x; 1.8142x over previous
//
#include <hip/hip_runtime.h>
#include <hip/hip_bf16.h>
#include <cstdint>

#define DEVINL __device__ __forceinline__

namespace {
constexpr int B = 4, T = 256, U = 101, V = 1024;
constexpr int BLANK = 1023;
constexpr float SIGMA = 0.05f;
constexpr float NEG_INF = -1.0e30f;
constexpr int TU = T * U;
constexpr int BTU = B * TU;
constexpr int KD = T + U - 1;    // 356 diagonals to process
constexpr int KP = 360;          // padded diagonal rows per batch (fits k+d+1 writes)
constexpr int UP = 128;          // padded u stride
constexpr int PS = B * KP * UP;  // plane size (floats)
constexpr int NPL = 9;           // planes: E, SG1..4, MG1..4
constexpr float INV_LN2 = 1.4426950408889634f;
constexpr float LN2 = 0.6931471805599453f;
}

// pairwise logaddexp in base-2
DEVINL float lae2(float a, float b) {
  float m = fmaxf(a, b);
  return m + log2f(1.0f + exp2f(fminf(a, b) - m));
}

// 9-edge logsumexp in base-2 (one cell of the DP)
DEVINL float cell_lse(float st1, float st2, float st3, float st4,
                      float mv1, float mv2, float mv3, float mv4, float ch) {
  float m1 = fmaxf(fmaxf(st1, st2), fmaxf(st3, st4));
  float m2 = fmaxf(fmaxf(mv1, mv2), fmaxf(mv3, mv4));
  float m = fmaxf(fmaxf(m1, m2), ch);
  float s = exp2f(st1 - m) + exp2f(st2 - m) + exp2f(st3 - m) + exp2f(st4 - m) +
            exp2f(mv1 - m) + exp2f(mv2 - m) + exp2f(mv3 - m) + exp2f(mv4 - m) +
            exp2f(ch - m);
  return m + log2f(s);
}

// ---------------- K0: fill diagonal workspace with NEG_INF ----------------
__global__ void __launch_bounds__(256) k_fill(float* __restrict__ w) {
  int i = blockIdx.x * 256 + threadIdx.x;
  if (i < NPL * PS / 4) {
    float4 v = {NEG_INF, NEG_INF, NEG_INF, NEG_INF};
    reinterpret_cast<float4*>(w)[i] = v;
  }
}

// ---------------- K1: per-(b,t,u) row reduction -> diagonal-major operands ----
// one wave per row of 1029 floats. Operand planes are ARRIVAL-centric:
//   E  [k][u] = e0[t][u-1]        (k = t+u)     chain edge into (t,u)
//   SG_d[k][u] = stay_d[t-d][u]                  blank edge into (t,u)
//   MG_d[k][u] = move_d[t-d][u-1]                label edge into (t,u)
// all values pre-scaled by 1/ln2 for base-2 DP.
__global__ void __launch_bounds__(256) k_prep(
    const float* __restrict__ acts, const int* __restrict__ labels,
    float* __restrict__ diag) {
  int gwave = (blockIdx.x * 256 + threadIdx.x) >> 6;
  int lane = threadIdx.x & 63;
  if (gwave >= BTU) return;
  int b = gwave / TU;
  int rem = gwave - b * TU;
  int t = rem / U;
  int u = rem - t * U;
  const float* row = acts + (size_t)gwave * (V + 5);

  float x[16];
#pragma unroll
  for (int j = 0; j < 16; ++j) x[j] = row[j * 64 + lane];
  float m = x[0];
#pragma unroll
  for (int j = 1; j < 16; ++j) m = fmaxf(m, x[j]);
#pragma unroll
  for (int off = 32; off >= 1; off >>= 1) m = fmaxf(m, __shfl_xor(m, off, 64));
  float s = 0.f;
#pragma unroll
  for (int j = 0; j < 16; ++j) s += __expf(x[j] - m);
#pragma unroll
  for (int off = 32; off >= 1; off >>= 1) s += __shfl_xor(s, off, 64);
  float lse = m + __logf(s);

  if (lane == 0) {
    float blank = row[BLANK];
    int lab = (u < U - 1) ? labels[b * (U - 1) + u] : 0;
    float y = row[lab];
    float d0 = row[V], d1 = row[V + 1], d2 = row[V + 2], d3 = row[V + 3], d4 = row[V + 4];
    float dm = fmaxf(fmaxf(fmaxf(d0, d1), fmaxf(d2, d3)), d4);
    float dl = dm + __logf(__expf(d0 - dm) + __expf(d1 - dm) + __expf(d2 - dm) +
                           __expf(d3 - dm) + __expf(d4 - dm));
    float bl = blank - lse - SIGMA;  // blank_lp
    float yl = y - lse - SIGMA;      // y_lp
    int k = t + u;
    size_t base = (size_t)b * KP;
    diag[1 * PS + (base + k + 1) * UP + u] = (bl + d1 - dl) * INV_LN2;
    diag[2 * PS + (base + k + 2) * UP + u] = (bl + d2 - dl) * INV_LN2;
    diag[3 * PS + (base + k + 3) * UP + u] = (bl + d3 - dl) * INV_LN2;
    diag[4 * PS + (base + k + 4) * UP + u] = (bl + d4 - dl) * INV_LN2;
    if (u + 1 < U) {
      diag[0 * PS + (base + k + 1) * UP + u + 1] = (yl + d0 - dl) * INV_LN2;
      diag[5 * PS + (base + k + 2) * UP + u + 1] = (yl + d1 - dl) * INV_LN2;
      diag[6 * PS + (base + k + 3) * UP + u + 1] = (yl + d2 - dl) * INV_LN2;
      diag[7 * PS + (base + k + 4) * UP + u + 1] = (yl + d3 - dl) * INV_LN2;
      diag[8 * PS + (base + k + 5) * UP + u + 1] = (yl + d4 - dl) * INV_LN2;
    }
  }
}

// ---------------- K2: diagonal-wavefront DP, one wave per batch ----------------
struct Ops {
  float E0, E1, S10, S11, S20, S21, S30, S31, S40, S41,
        M10, M11, M20, M21, M30, M31, M40, M41;
};

DEVINL Ops load_ops(const float* __restrict__ pE, const float* __restrict__ pS1,
                    const float* __restrict__ pS2, const float* __restrict__ pS3,
                    const float* __restrict__ pS4, const float* __restrict__ pM1,
                    const float* __restrict__ pM2, const float* __restrict__ pM3,
                    const float* __restrict__ pM4, int off, int l) {
  Ops o;
  int i0 = off + l, i1 = off + 64 + l;
  o.E0 = pE[i0];  o.E1 = pE[i1];
  o.S10 = pS1[i0]; o.S11 = pS1[i1];
  o.S20 = pS2[i0]; o.S21 = pS2[i1];
  o.S30 = pS3[i0]; o.S31 = pS3[i1];
  o.S40 = pS4[i0]; o.S41 = pS4[i1];
  o.M10 = pM1[i0]; o.M11 = pM1[i1];
  o.M20 = pM2[i0]; o.M21 = pM2[i1];
  o.M30 = pM3[i0]; o.M31 = pM3[i1];
  o.M40 = pM4[i0]; o.M41 = pM4[i1];
  return o;
}

__global__ void __launch_bounds__(64, 1) k_dp(
    const float* __restrict__ diag, const int* __restrict__ act_lens,
    const int* __restrict__ label_lens, float* __restrict__ partial) {
  const int b = blockIdx.x;
  const int l = threadIdx.x;
  const int al = act_lens[b];
  const int ll = label_lens[b];
  const size_t boff = (size_t)b * KP * UP;
  const float* pE = diag + 0 * PS + boff;
  const float* pS1 = diag + 1 * PS + boff;
  const float* pS2 = diag + 2 * PS + boff;
  const float* pS3 = diag + 3 * PS + boff;
  const float* pS4 = diag + 4 * PS + boff;
  const float* pM1 = diag + 5 * PS + boff;
  const float* pM2 = diag + 6 * PS + boff;
  const float* pM3 = diag + 7 * PS + boff;
  const float* pM4 = diag + 8 * PS + boff;

  // final-term stays: SG_d[al+ll][ll] == stay_d[al-d][ll] for all d
  float sgf1 = pS1[(al + ll) * UP + ll];
  float sgf2 = pS2[(al + ll) * UP + ll];
  float sgf3 = pS3[(al + ll) * UP + ll];
  float sgf4 = pS4[(al + ll) * UP + ll];
  const bool isLL0 = (l == ll);
  const bool isLL1 = (l + 64 == ll);
  const int kbase = al - 4 + ll;

  // alpha history rings: r = own diag values, q = shifted (u-1) diag values
  float r0h1 = NEG_INF, r0h2 = NEG_INF, r0h3 = NEG_INF, r0h4 = NEG_INF;
  float r1h1 = NEG_INF, r1h2 = NEG_INF, r1h3 = NEG_INF, r1h4 = NEG_INF;
  float q0h1 = NEG_INF, q0h2 = NEG_INF, q0h3 = NEG_INF, q0h4 = NEG_INF, q0h5 = NEG_INF;
  float q1h1 = NEG_INF, q1h2 = NEG_INF, q1h3 = NEG_INF, q1h4 = NEG_INF, q1h5 = NEG_INF;
  float tAcc = NEG_INF;
  float init0 = (l == 0) ? 0.0f : NEG_INF;  // DP seed at (t=0,u=0), first diagonal only

  // depth-3 register prefetch queue
  Ops c0 = load_ops(pE, pS1, pS2, pS3, pS4, pM1, pM2, pM3, pM4, 0, l);
  Ops p1 = load_ops(pE, pS1, pS2, pS3, pS4, pM1, pM2, pM3, pM4, UP, l);
  Ops p2 = load_ops(pE, pS1, pS2, pS3, pS4, pM1, pM2, pM3, pM4, 2 * UP, l);

#pragma unroll 4
  for (int k = 0; k < KD; ++k) {
    Ops p3 = load_ops(pE, pS1, pS2, pS3, pS4, pM1, pM2, pM3, pM4, (k + 3) * UP, l);

    // slot0: u = l, t = k - l
    float st1 = r0h1 + c0.S10, st2 = r0h2 + c0.S20, st3 = r0h3 + c0.S30, st4 = r0h4 + c0.S40;
    float mv1 = q0h2 + c0.M10, mv2 = q0h3 + c0.M20, mv3 = q0h4 + c0.M30, mv4 = q0h5 + c0.M40;
    float ch = q0h1 + c0.E0;
    float r0 = cell_lse(st1, st2, st3, st4, mv1, mv2, mv3, mv4, ch);
    int t0 = k - l;
    r0 = (t0 >= 0 && t0 < T) ? fmaxf(r0, init0) : NEG_INF;

    // slot1: u = 64 + l, t = k - 64 - l
    float su1 = r1h1 + c0.S11, su2 = r1h2 + c0.S21, su3 = r1h3 + c0.S31, su4 = r1h4 + c0.S41;
    float mu1 = q1h2 + c0.M11, mu2 = q1h3 + c0.M21, mu3 = q1h4 + c0.M31, mu4 = q1h5 + c0.M41;
    float chu = q1h1 + c0.E1;
    float r1 = cell_lse(su1, su2, su3, su4, mu1, mu2, mu3, mu4, chu);
    int t1 = t0 - 64;
    r1 = (t1 >= 0 && t1 < T && l + 64 < U) ? r1 : NEG_INF;

    // final-term capture: alpha[al-d][ll] + stay_d[al-d][ll], at k = al-d+ll
    unsigned idx = (unsigned)(k - kbase);
    if (idx < 4u) {
      float sg = (idx == 0) ? sgf4 : (idx == 1) ? sgf3 : (idx == 2) ? sgf2 : sgf1;
      if (isLL0) tAcc = lae2(tAcc, r0 + sg);
      if (isLL1) tAcc = lae2(tAcc, r1 + sg);
    }

    // shifted (u-1) values of this diagonal
    float s0 = __shfl_up(r0, 1, 64);
    float top = __shfl(r0, 63, 64);  // r at u=63, feeds u=64's neighbor
    float s1 = __shfl_up(r1, 1, 64);
    if (l == 0) { s0 = NEG_INF; s1 = top; }

    // rotate rings + prefetch queue
    r0h4 = r0h3; r0h3 = r0h2; r0h2 = r0h1; r0h1 = r0;
    r1h4 = r1h3; r1h3 = r1h2; r1h2 = r1h1; r1h1 = r1;
    q0h5 = q0h4; q0h4 = q0h3; q0h3 = q0h2; q0h2 = q0h1; q0h1 = s0;
    q1h5 = q1h4; q1h4 = q1h3; q1h3 = q1h2; q1h2 = q1h1; q1h1 = s1;
    c0 = p1; p1 = p2; p2 = p3;
    init0 = NEG_INF;
  }

  if (isLL0 | isLL1) partial[b] = -tAcc * LN2;
}

// ---------------- K3: batch reduce ----------------
__global__ void k_final(const float* __restrict__ partial, float* __restrict__ out) {
  if (threadIdx.x == 0 && blockIdx.x == 0)
    out[0] = (partial[0] + partial[1] + partial[2] + partial[3]) * 0.25f;
}

extern "C" void kernel_launch(void* const* d_in, const int* in_sizes, int n_in,
                              void* d_out, int out_size, void* d_ws, size_t ws_size,
                              hipStream_t stream) {
  const float* acts = (const float*)d_in[0];
  const int* labels = (const int*)d_in[1];
  const int* act_lens = (const int*)d_in[2];
  const int* label_lens = (const int*)d_in[3];
  float* diag = (float*)d_ws;                 // [9][B][KP][UP]
  float* partial = diag + (size_t)NPL * PS;   // [B]
  float* out = (float*)d_out;

  k_fill<<<(NPL * PS / 4 + 255) / 256, 256, 0, stream>>>(diag);
  k_prep<<<BTU / 4, 256, 0, stream>>>(acts, labels, diag);
  k_dp<<<B, 64, 0, stream>>>(diag, act_lens, label_lens, partial);
  k_final<<<1, 64, 0, stream>>>(partial, out);
}

// Round 4
// 196.144 us; speedup vs baseline: 2.4578x; 1.3548x over previous
//
#include <hip/hip_runtime.h>
#include <hip/hip_bf16.h>
#include <cstdint>

#define DEVINL __device__ __forceinline__

namespace {
constexpr int B = 4, T = 256, U = 101, V = 1024;
constexpr int BLANK = 1023;
constexpr float SIGMA = 0.05f;
constexpr int TU = T * U;
constexpr int BTU = B * TU;
constexpr int KD = T + U - 1;    // 356 diagonals
constexpr int KP = 368;          // padded diag rows per batch (max write row = k+5 = 360)
constexpr int UP = 128;          // padded u stride
constexpr int PS = B * KP * UP;  // cells per plane group
constexpr float LN2 = 0.6931471805599453f;
}

// zero-safe mantissa/exponent split: x = m * 2^e with m in [1,2) (or m=0)
DEVINL void renorm(float x, float& m, int& e) {
  uint32_t bits = __float_as_uint(x);
  int ef = (int)((bits >> 23) & 0xffu);
  float mm = __uint_as_float((bits & 0x807fffffu) | 0x3f800000u);
  m = (ef == 0) ? 0.0f : mm;   // denormals flattened to 0 (irrelevant mass)
  e = ef - 127;
}

// ---------------- K0: zero-fill weight planes ----------------
__global__ void __launch_bounds__(256) k_fill(float4* __restrict__ w, int n4) {
  int i = blockIdx.x * 256 + threadIdx.x;
  if (i < n4) w[i] = float4{0.f, 0.f, 0.f, 0.f};
}

// ---------------- K1: softmax rows -> LINEAR-domain diagonal weight planes ----
// Destination-centric, u-SHIFTED for E/M:
//  PSv[k][u] = {S1,S2,S3,S4}: stay_d weight into cell (t=k-u, u)
//  PMv[k][j] = {E,M1,M2,M3}:  chain/move weights into cell (k, j+1)  [shifted!]
//  PM4[k][j] = M4 weight into cell (k, j+1)
__global__ void __launch_bounds__(256) k_prep(
    const float* __restrict__ acts, const int* __restrict__ labels,
    float* __restrict__ PSvF, float* __restrict__ PMvF, float* __restrict__ PM4) {
  int gwave = (blockIdx.x * 256 + threadIdx.x) >> 6;
  int lane = threadIdx.x & 63;
  if (gwave >= BTU) return;
  int b = gwave / TU;
  int rem = gwave - b * TU;
  int t = rem / U;
  int u = rem - t * U;
  const float* row = acts + (size_t)gwave * (V + 5);

  float x[16];
#pragma unroll
  for (int j = 0; j < 16; ++j) x[j] = row[j * 64 + lane];
  float m = x[0];
#pragma unroll
  for (int j = 1; j < 16; ++j) m = fmaxf(m, x[j]);
#pragma unroll
  for (int off = 32; off >= 1; off >>= 1) m = fmaxf(m, __shfl_xor(m, off, 64));
  float s = 0.f;
#pragma unroll
  for (int j = 0; j < 16; ++j) s += __expf(x[j] - m);
#pragma unroll
  for (int off = 32; off >= 1; off >>= 1) s += __shfl_xor(s, off, 64);

  if (lane == 0) {
    float inv_s = 1.0f / s;
    // label-softmax probs, under-normalized by sigma (exp(lp) forms, no log needed)
    float pb = __expf(row[BLANK] - m - SIGMA) * inv_s;               // exp(blank_lp)
    int lab = (u < U - 1) ? labels[b * (U - 1) + u] : 0;
    float py = __expf(row[lab] - m - SIGMA) * inv_s;                 // exp(y_lp)
    // duration softmax
    float d0 = row[V], d1 = row[V + 1], d2 = row[V + 2], d3 = row[V + 3], d4 = row[V + 4];
    float dm = fmaxf(fmaxf(fmaxf(d0, d1), fmaxf(d2, d3)), d4);
    float e0x = __expf(d0 - dm), e1x = __expf(d1 - dm), e2x = __expf(d2 - dm),
          e3x = __expf(d3 - dm), e4x = __expf(d4 - dm);
    float invd = 1.0f / (e0x + e1x + e2x + e3x + e4x);
    float q0 = e0x * invd, q1 = e1x * invd, q2 = e2x * invd, q3 = e3x * invd, q4 = e4x * invd;

    int base = b * KP + t + u;
    int c1 = ((base + 1) * UP + u) * 4;
    int c2 = ((base + 2) * UP + u) * 4;
    int c3 = ((base + 3) * UP + u) * 4;
    int c4 = ((base + 4) * UP + u) * 4;
    PSvF[c1 + 0] = pb * q1;  PSvF[c2 + 1] = pb * q2;
    PSvF[c3 + 2] = pb * q3;  PSvF[c4 + 3] = pb * q4;
    PMvF[c1 + 0] = py * q0;  PMvF[c2 + 1] = py * q1;   // E', M1'
    PMvF[c3 + 2] = py * q2;  PMvF[c4 + 3] = py * q3;   // M2', M3'
    PM4[(base + 5) * UP + u] = py * q4;                // M4'
  }
}

// ---------------- K2: linear-domain diagonal DP, one wave per batch ----------------
struct Ops {
  float4 s0, m0; float w40;   // slot0 (u = l)
  float4 s1, m1; float w41;   // slot1 (u = 64 + l)
};

DEVINL Ops load_ops(const float4* __restrict__ pS, const float4* __restrict__ pM,
                    const float* __restrict__ p4, int rowbase, int l) {
  Ops o;
  int i0 = rowbase + l, i1 = rowbase + 64 + l;
  o.s0 = pS[i0]; o.m0 = pM[i0]; o.w40 = p4[i0];
  o.s1 = pS[i1]; o.m1 = pM[i1]; o.w41 = p4[i1];
  return o;
}

__global__ void __launch_bounds__(64, 1) k_dp(
    const float4* __restrict__ PSv, const float4* __restrict__ PMv,
    const float* __restrict__ PM4, const int* __restrict__ act_lens,
    const int* __restrict__ label_lens, float* __restrict__ partial) {
  const int b = blockIdx.x;
  const int l = threadIdx.x;
  const int al = act_lens[b];
  const int ll = label_lens[b];
  const int cb = b * KP * UP;
  const float4* pS = PSv + cb;
  const float4* pM = PMv + cb;
  const float* p4 = PM4 + cb;

  // final-term stay weights: S_d at cell (al-d, ll) live at row al+ll, col ll
  const float4 sgf = pS[(al + ll) * UP + ll];   // {S1,S2,S3,S4}
  const bool isLL0 = (l == ll);
  const bool isLL1 = (l + 64 == ll);
  const int kbase = al + ll - 4;

  // alpha history rings (mantissas at shared per-lane offset o)
  float h01 = 0, h02 = 0, h03 = 0, h04 = 0, h05 = 0; int o0 = 0;
  float h11 = 0, h12 = 0, h13 = 0, h14 = 0, h15 = 0; int o1 = 0;
  float tAm = 0.f; int tAo = -(1 << 28);

  Ops c0 = load_ops(pS, pM, p4, 0 * UP, l);
  Ops q1 = load_ops(pS, pM, p4, 1 * UP, l);
  Ops q2 = load_ops(pS, pM, p4, 2 * UP, l);

#pragma unroll 4
  for (int k = 0; k < KD; ++k) {
    Ops q3 = load_ops(pS, pM, p4, (k + 3) * UP, l);

    const bool s0on = (k <= T + 62);   // slot0 cells/help dead after k=318+seam@319
    const bool s1on = (k >= 64);       // slot1 cells start at k>=64 (u>=64)

    float help0 = 0.f, sv = 0.f; int so = 0;
    if (s0on) {
      // self: stay edges (same u); help: chain/move edges for RIGHT neighbor (u=l+1)
      float self0 = fmaf(h01, c0.s0.x, fmaf(h02, c0.s0.y, fmaf(h03, c0.s0.z, h04 * c0.s0.w)));
      help0 = fmaf(h01, c0.m0.x, fmaf(h02, c0.m0.y,
               fmaf(h03, c0.m0.z, fmaf(h04, c0.m0.w, h05 * c0.w40))));
      float snb = __shfl_up(help0, 1, 64);
      int onb = __shfl_up(o0, 1, 64);
      if (s1on) { sv = __shfl(help0, 63, 64); so = __shfl(o0, 63, 64); }
      snb = (l == 0) ? 0.0f : snb;
      onb = (l == 0) ? o0 : onb;
      int bb = (o0 > onb) ? o0 : onb;
      float seed = (k == 0 && l == 0) ? 1.0f : 0.0f;
      float rraw = ldexpf(self0, o0 - bb) + ldexpf(snb, onb - bb) + seed;
      float mn; int en; renorm(rraw, mn, en);
      mn = ((unsigned)(k - l) < (unsigned)T) ? mn : 0.0f;   // t-range guard
      int on = bb + en;
      unsigned idx = (unsigned)(k - kbase);
      if (idx < 4u && isLL0) {  // term_d = alpha(al-d,ll) * S_d(al-d,ll)
        float sg = (idx == 0) ? sgf.w : (idx == 1) ? sgf.z : (idx == 2) ? sgf.y : sgf.x;
        float tm = mn * sg; int to = on;
        int nb2 = (tAo > to) ? tAo : to;
        tAm = ldexpf(tAm, tAo - nb2) + ldexpf(tm, to - nb2);
        tAo = nb2;
      }
      int dd = o0 - on;   // rescale carried history to new offset
      h05 = ldexpf(h04, dd); h04 = ldexpf(h03, dd);
      h03 = ldexpf(h02, dd); h02 = ldexpf(h01, dd);
      h01 = mn; o0 = on;
    }

    if (s1on) {
      float self1 = fmaf(h11, c0.s1.x, fmaf(h12, c0.s1.y, fmaf(h13, c0.s1.z, h14 * c0.s1.w)));
      float help1 = fmaf(h11, c0.m1.x, fmaf(h12, c0.m1.y,
                     fmaf(h13, c0.m1.z, fmaf(h14, c0.m1.w, h15 * c0.w41))));
      float snb = __shfl_up(help1, 1, 64);
      int onb = __shfl_up(o1, 1, 64);
      snb = (l == 0) ? sv : snb;    // seam: u=64's left neighbor is slot0 lane 63
      onb = (l == 0) ? so : onb;
      int bb = (o1 > onb) ? o1 : onb;
      float rraw = ldexpf(self1, o1 - bb) + ldexpf(snb, onb - bb);
      float mn; int en; renorm(rraw, mn, en);
      bool v1 = ((unsigned)(k - 64 - l) < (unsigned)T) && (l + 64 < U);
      mn = v1 ? mn : 0.0f;
      int on = bb + en;
      unsigned idx = (unsigned)(k - kbase);
      if (idx < 4u && isLL1) {
        float sg = (idx == 0) ? sgf.w : (idx == 1) ? sgf.z : (idx == 2) ? sgf.y : sgf.x;
        float tm = mn * sg; int to = on;
        int nb2 = (tAo > to) ? tAo : to;
        tAm = ldexpf(tAm, tAo - nb2) + ldexpf(tm, to - nb2);
        tAo = nb2;
      }
      int dd = o1 - on;
      h15 = ldexpf(h14, dd); h14 = ldexpf(h13, dd);
      h13 = ldexpf(h12, dd); h12 = ldexpf(h11, dd);
      h11 = mn; o1 = on;
    }

    c0 = q1; q1 = q2; q2 = q3;
  }

  if (isLL0 || isLL1) {
    // loglike = ln(tAm * 2^tAo)
    partial[b] = -(log2f(tAm) + (float)tAo) * LN2;
  }
}

// ---------------- K3: batch reduce ----------------
__global__ void k_final(const float* __restrict__ partial, float* __restrict__ out) {
  if (threadIdx.x == 0 && blockIdx.x == 0)
    out[0] = (partial[0] + partial[1] + partial[2] + partial[3]) * 0.25f;
}

extern "C" void kernel_launch(void* const* d_in, const int* in_sizes, int n_in,
                              void* d_out, int out_size, void* d_ws, size_t ws_size,
                              hipStream_t stream) {
  const float* acts = (const float*)d_in[0];
  const int* labels = (const int*)d_in[1];
  const int* act_lens = (const int*)d_in[2];
  const int* label_lens = (const int*)d_in[3];
  float* ws = (float*)d_ws;
  float* PSvF = ws;                       // [KP*B][UP] x float4 (S1..S4)
  float* PMvF = ws + 4 * (size_t)PS;      // [KP*B][UP] x float4 (E,M1,M2,M3) shifted
  float* PM4 = ws + 8 * (size_t)PS;       // [KP*B][UP] floats (M4) shifted
  float* partial = ws + 9 * (size_t)PS;   // [B]
  float* out = (float*)d_out;

  int n4 = 9 * PS / 4;
  k_fill<<<(n4 + 255) / 256, 256, 0, stream>>>(reinterpret_cast<float4*>(ws), n4);
  k_prep<<<BTU / 4, 256, 0, stream>>>(acts, labels, PSvF, PMvF, PM4);
  k_dp<<<B, 64, 0, stream>>>(reinterpret_cast<const float4*>(PSvF),
                             reinterpret_cast<const float4*>(PMvF), PM4,
                             act_lens, label_lens, partial);
  k_final<<<1, 64, 0, stream>>>(partial, out);
}

// Round 5
// 179.666 us; speedup vs baseline: 2.6832x; 1.0917x over previous
//
#include <hip/hip_runtime.h>
#include <hip/hip_bf16.h>
#include <cstdint>

#define DEVINL __device__ __forceinline__

namespace {
constexpr int B = 4, T = 256, U = 101, V = 1024;
constexpr int BLANK = 1023;
constexpr float SIGMA = 0.05f;
constexpr int TU = T * U;
constexpr int BTU = B * TU;
constexpr int KD = 360;          // padded loop count (356 real diagonals)
constexpr int KP = 368;          // padded diag rows per batch (max touched row = 367)
constexpr int UP = 128;          // padded u stride
constexpr int PS = B * KP * UP;  // cells per plane group
constexpr float LN2 = 0.6931471805599453f;
}

// zero-safe mantissa/exponent split: x = m * 2^e with m in [1,2) (or m=0)
DEVINL void renorm(float x, float& m, int& e) {
  uint32_t bits = __float_as_uint(x);
  int ef = (int)((bits >> 23) & 0xffu);
  float mm = __uint_as_float((bits & 0x807fffffu) | 0x3f800000u);
  m = (ef == 0) ? 0.0f : mm;   // denormals flattened to 0 (irrelevant mass)
  e = ef - 127;
}

// ---------------- K0: zero-fill weight planes ----------------
__global__ void __launch_bounds__(256) k_fill(float4* __restrict__ w, int n4) {
  int i = blockIdx.x * 256 + threadIdx.x;
  if (i < n4) w[i] = float4{0.f, 0.f, 0.f, 0.f};
}

// ---------------- K1: softmax rows -> LINEAR-domain diagonal weight planes ----
// Interleaved column mapping col(u) = (u&1)*64 + (u>>1): lane l of k_dp reads
// col l (u=2l) and col 64+l (u=2l+1) -> coalesced.
//  PSv[k][col(u)] = {S1..S4}: stay_d weight into cell (t=k-u, u)
//  PMv[k][col(u)] = {E,M1,M2,M3}: chain/move weights from column u into (.., u+1)
//  PM4[k][col(u)] = M4 likewise
__global__ void __launch_bounds__(256) k_prep(
    const float* __restrict__ acts, const int* __restrict__ labels,
    float* __restrict__ PSvF, float* __restrict__ PMvF, float* __restrict__ PM4) {
  int gwave = (blockIdx.x * 256 + threadIdx.x) >> 6;
  int lane = threadIdx.x & 63;
  if (gwave >= BTU) return;
  int b = gwave / TU;
  int rem = gwave - b * TU;
  int t = rem / U;
  int u = rem - t * U;
  const float* row = acts + (size_t)gwave * (V + 5);

  float x[16];
#pragma unroll
  for (int j = 0; j < 16; ++j) x[j] = row[j * 64 + lane];
  float m = x[0];
#pragma unroll
  for (int j = 1; j < 16; ++j) m = fmaxf(m, x[j]);
#pragma unroll
  for (int off = 32; off >= 1; off >>= 1) m = fmaxf(m, __shfl_xor(m, off, 64));
  float s = 0.f;
#pragma unroll
  for (int j = 0; j < 16; ++j) s += __expf(x[j] - m);
#pragma unroll
  for (int off = 32; off >= 1; off >>= 1) s += __shfl_xor(s, off, 64);

  if (lane == 0) {
    float inv_s = 1.0f / s;
    float pb = __expf(row[BLANK] - m - SIGMA) * inv_s;               // exp(blank_lp)
    int lab = (u < U - 1) ? labels[b * (U - 1) + u] : 0;
    float py = __expf(row[lab] - m - SIGMA) * inv_s;                 // exp(y_lp)
    float d0 = row[V], d1 = row[V + 1], d2 = row[V + 2], d3 = row[V + 3], d4 = row[V + 4];
    float dm = fmaxf(fmaxf(fmaxf(d0, d1), fmaxf(d2, d3)), d4);
    float e0x = __expf(d0 - dm), e1x = __expf(d1 - dm), e2x = __expf(d2 - dm),
          e3x = __expf(d3 - dm), e4x = __expf(d4 - dm);
    float invd = 1.0f / (e0x + e1x + e2x + e3x + e4x);
    float q0 = e0x * invd, q1 = e1x * invd, q2 = e2x * invd, q3 = e3x * invd, q4 = e4x * invd;

    int col = ((u & 1) << 6) | (u >> 1);
    int base = b * KP + t + u;
    int c1 = ((base + 1) * UP + col) * 4;
    int c2 = ((base + 2) * UP + col) * 4;
    int c3 = ((base + 3) * UP + col) * 4;
    int c4 = ((base + 4) * UP + col) * 4;
    PSvF[c1 + 0] = pb * q1;  PSvF[c2 + 1] = pb * q2;
    PSvF[c3 + 2] = pb * q3;  PSvF[c4 + 3] = pb * q4;
    if (u + 1 < U) {
      PMvF[c1 + 0] = py * q0;  PMvF[c2 + 1] = py * q1;   // E, M1
      PMvF[c3 + 2] = py * q2;  PMvF[c4 + 3] = py * q3;   // M2, M3
      PM4[(base + 5) * UP + col] = py * q4;              // M4
    }
  }
}

// ---------------- K2: linear-domain diagonal DP, one wave per batch ----------------
struct Ops {
  float4 s0, m0; float w40;   // slot0 (u = 2l)
  float4 s1, m1; float w41;   // slot1 (u = 2l+1)
};

DEVINL Ops load_ops(const float4* __restrict__ pS, const float4* __restrict__ pM,
                    const float* __restrict__ p4, int rowbase, int l) {
  Ops o;
  int i0 = rowbase + l, i1 = rowbase + 64 + l;
  o.s0 = pS[i0]; o.m0 = pM[i0]; o.w40 = p4[i0];
  o.s1 = pS[i1]; o.m1 = pM[i1]; o.w41 = p4[i1];
  return o;
}

__global__ void __launch_bounds__(64, 1) k_dp(
    const float4* __restrict__ PSv, const float4* __restrict__ PMv,
    const float* __restrict__ PM4, const int* __restrict__ act_lens,
    const int* __restrict__ label_lens, float* __restrict__ partial) {
  const int b = blockIdx.x;
  const int l = threadIdx.x;
  const int al = act_lens[b];
  const int ll = label_lens[b];
  const int cb = b * KP * UP;
  const float4* pS = PSv + cb;
  const float4* pM = PMv + cb;
  const float* p4 = PM4 + cb;

  const int cll = ((ll & 1) << 6) | (ll >> 1);
  const float4 sgf = pS[(al + ll) * UP + cll];   // {S1,S2,S3,S4} at dest (al,ll)
  const int u0 = 2 * l, u1 = 2 * l + 1;
  const bool isLL0 = (u0 == ll);
  const bool isLL1 = (u1 == ll);
  const int kbase = al + ll - 4;

  // alpha history rings (mantissas at shared per-lane offset o)
  float h01 = 0, h02 = 0, h03 = 0, h04 = 0, h05 = 0; int o0 = 0;
  float h11 = 0, h12 = 0, h13 = 0, h14 = 0, h15 = 0; int o1 = 0;
  float tAm = 0.f; int tAo = -(1 << 28);

  // depth-8 register prefetch ring
  Ops q[8];
#pragma unroll
  for (int j = 0; j < 8; ++j) q[j] = load_ops(pS, pM, p4, j * UP, l);

  for (int kb = 0; kb < KD; kb += 8) {
#pragma unroll
    for (int j = 0; j < 8; ++j) {
      const int k = kb + j;
      Ops cur = q[j];
      q[j] = load_ops(pS, pM, p4, (k + 8) * UP, l);  // row <= 367 < KP

      // edge sums from OLD history
      float help0 = fmaf(h01, cur.m0.x, fmaf(h02, cur.m0.y,
                     fmaf(h03, cur.m0.z, fmaf(h04, cur.m0.w, h05 * cur.w40))));
      float help1 = fmaf(h11, cur.m1.x, fmaf(h12, cur.m1.y,
                     fmaf(h13, cur.m1.z, fmaf(h14, cur.m1.w, h15 * cur.w41))));
      float self0 = fmaf(h01, cur.s0.x, fmaf(h02, cur.s0.y, fmaf(h03, cur.s0.z, h04 * cur.s0.w)));
      float self1 = fmaf(h11, cur.s1.x, fmaf(h12, cur.s1.y, fmaf(h13, cur.s1.z, h14 * cur.s1.w)));

      // slot0 neighbor (u=2l-1) = slot1 of lane l-1
      float n0 = __shfl_up(help1, 1, 64);
      int on0 = __shfl_up(o1, 1, 64);
      n0 = (l == 0) ? 0.0f : n0;
      on0 = (l == 0) ? o0 : on0;

      // slot0 combine
      int bb0 = (o0 > on0) ? o0 : on0;
      float r0 = ldexpf(self0, o0 - bb0) + ldexpf(n0, on0 - bb0);
      if (k == 0 && l == 0) r0 += 1.0f;              // DP seed at (t=0,u=0)
      float mn0; int en0; renorm(r0, mn0, en0);
      mn0 = ((unsigned)(k - u0) < (unsigned)T && u0 < U) ? mn0 : 0.0f;
      int no0 = bb0 + en0;

      // slot1 combine (neighbor u=2l = same-lane help0 @ o0)
      int bb1 = (o1 > o0) ? o1 : o0;
      float r1 = ldexpf(self1, o1 - bb1) + ldexpf(help0, o0 - bb1);
      float mn1; int en1; renorm(r1, mn1, en1);
      mn1 = ((unsigned)(k - u1) < (unsigned)T && u1 < U) ? mn1 : 0.0f;
      int no1 = bb1 + en1;

      // final-term capture: alpha(al-d,ll) * S_d(al-d,ll) at k = al-d+ll
      unsigned idx = (unsigned)(k - kbase);
      if (idx < 4u) {
        float sg = (idx == 0) ? sgf.w : (idx == 1) ? sgf.z : (idx == 2) ? sgf.y : sgf.x;
        if (isLL0 | isLL1) {
          float tm = (isLL0 ? mn0 : mn1) * sg;
          int to = isLL0 ? no0 : no1;
          int nb2 = (tAo > to) ? tAo : to;
          tAm = ldexpf(tAm, tAo - nb2) + ldexpf(tm, to - nb2);
          tAo = nb2;
        }
      }

      // push histories (rescale to new offset)
      int dd0 = o0 - no0;
      h05 = ldexpf(h04, dd0); h04 = ldexpf(h03, dd0);
      h03 = ldexpf(h02, dd0); h02 = ldexpf(h01, dd0);
      h01 = mn0; o0 = no0;
      int dd1 = o1 - no1;
      h15 = ldexpf(h14, dd1); h14 = ldexpf(h13, dd1);
      h13 = ldexpf(h12, dd1); h12 = ldexpf(h11, dd1);
      h11 = mn1; o1 = no1;
    }
  }

  if (isLL0 | isLL1) partial[b] = -(log2f(tAm) + (float)tAo) * LN2;
}

// ---------------- K3: batch reduce ----------------
__global__ void k_final(const float* __restrict__ partial, float* __restrict__ out) {
  if (threadIdx.x == 0 && blockIdx.x == 0)
    out[0] = (partial[0] + partial[1] + partial[2] + partial[3]) * 0.25f;
}

extern "C" void kernel_launch(void* const* d_in, const int* in_sizes, int n_in,
                              void* d_out, int out_size, void* d_ws, size_t ws_size,
                              hipStream_t stream) {
  const float* acts = (const float*)d_in[0];
  const int* labels = (const int*)d_in[1];
  const int* act_lens = (const int*)d_in[2];
  const int* label_lens = (const int*)d_in[3];
  float* ws = (float*)d_ws;
  float* PSvF = ws;                       // [B*KP][UP] x float4 (S1..S4)
  float* PMvF = ws + 4 * (size_t)PS;      // [B*KP][UP] x float4 (E,M1,M2,M3)
  float* PM4 = ws + 8 * (size_t)PS;       // [B*KP][UP] floats (M4)
  float* partial = ws + 9 * (size_t)PS;   // [B]
  float* out = (float*)d_out;

  int n4 = 9 * PS / 4;
  k_fill<<<(n4 + 255) / 256, 256, 0, stream>>>(reinterpret_cast<float4*>(ws), n4);
  k_prep<<<BTU / 4, 256, 0, stream>>>(acts, labels, PSvF, PMvF, PM4);
  k_dp<<<B, 64, 0, stream>>>(reinterpret_cast<const float4*>(PSvF),
                             reinterpret_cast<const float4*>(PMvF), PM4,
                             act_lens, label_lens, partial);
  k_final<<<1, 64, 0, stream>>>(partial, out);
}

// Round 6
// 168.457 us; speedup vs baseline: 2.8617x; 1.0665x over previous
//
#include <hip/hip_runtime.h>
#include <hip/hip_bf16.h>
#include <cstdint>

#define DEVINL __device__ __forceinline__

namespace {
constexpr int B = 4, T = 256, U = 101, V = 1024;
constexpr int BLANK = 1023;
constexpr float SIGMA = 0.05f;
constexpr int TU = T * U;
constexpr int BTU = B * TU;
constexpr int KD = 360;          // padded loop count (356 real diagonals), 12 | KD
constexpr int KP = 376;          // padded diag rows (max prefetch row = 359+12 = 371)
constexpr int UP = 128;          // padded u stride
constexpr int CELLS = B * KP * UP;
// ws layout (floats): A plane = CELLS int4 (8 bf16 each) -> CELLS*4 floats,
// M4 plane = CELLS ushort -> CELLS/2 floats, then partial[B]
constexpr int A_FLOATS = CELLS * 4;
constexpr int M4_FLOATS = CELLS / 2;
constexpr float LN2 = 0.6931471805599453f;
}

// zero-safe mantissa/exponent split: x = m * 2^e with m in [1,2) (or m=0)
DEVINL void renorm(float x, float& m, int& e) {
  uint32_t bits = __float_as_uint(x);
  int ef = (int)((bits >> 23) & 0xffu);
  float mm = __uint_as_float((bits & 0x807fffffu) | 0x3f800000u);
  m = (ef == 0) ? 0.0f : mm;   // denormals flattened to 0 (irrelevant mass)
  e = ef - 127;
}

DEVINL float lo16(int v) { return __uint_as_float(((uint32_t)v) << 16); }
DEVINL float hi16(int v) { return __uint_as_float(((uint32_t)v) & 0xffff0000u); }

// ---------------- K0: zero-fill weight planes ----------------
__global__ void __launch_bounds__(256) k_fill(float4* __restrict__ w, int n4) {
  int i = blockIdx.x * 256 + threadIdx.x;
  if (i < n4) w[i] = float4{0.f, 0.f, 0.f, 0.f};
}

// ---------------- K1: softmax rows -> bf16 diagonal weight planes ----
// Interleaved column mapping col(u) = (u&1)*64 + (u>>1); lane l of k_dp owns
// u=2l (col l) and u=2l+1 (col 64+l) -> coalesced 16B loads.
// A[row][col] = 8 bf16 {S1,S2,S3,S4, E,M1,M2,M3}; M4 plane separate (ushort).
__global__ void __launch_bounds__(256) k_prep(
    const float* __restrict__ acts, const int* __restrict__ labels,
    __hip_bfloat16* __restrict__ A, __hip_bfloat16* __restrict__ M4p) {
  int gwave = (blockIdx.x * 256 + threadIdx.x) >> 6;
  int lane = threadIdx.x & 63;
  if (gwave >= BTU) return;
  int b = gwave / TU;
  int rem = gwave - b * TU;
  int t = rem / U;
  int u = rem - t * U;
  const float* row = acts + (size_t)gwave * (V + 5);

  float x[16];
#pragma unroll
  for (int j = 0; j < 16; ++j) x[j] = row[j * 64 + lane];
  float m = x[0];
#pragma unroll
  for (int j = 1; j < 16; ++j) m = fmaxf(m, x[j]);
#pragma unroll
  for (int off = 32; off >= 1; off >>= 1) m = fmaxf(m, __shfl_xor(m, off, 64));
  float s = 0.f;
#pragma unroll
  for (int j = 0; j < 16; ++j) s += __expf(x[j] - m);
#pragma unroll
  for (int off = 32; off >= 1; off >>= 1) s += __shfl_xor(s, off, 64);

  if (lane == 0) {
    float inv_s = 1.0f / s;
    float pb = __expf(row[BLANK] - m - SIGMA) * inv_s;               // exp(blank_lp)
    int lab = (u < U - 1) ? labels[b * (U - 1) + u] : 0;
    float py = __expf(row[lab] - m - SIGMA) * inv_s;                 // exp(y_lp)
    float d0 = row[V], d1 = row[V + 1], d2 = row[V + 2], d3 = row[V + 3], d4 = row[V + 4];
    float dm = fmaxf(fmaxf(fmaxf(d0, d1), fmaxf(d2, d3)), d4);
    float e0x = __expf(d0 - dm), e1x = __expf(d1 - dm), e2x = __expf(d2 - dm),
          e3x = __expf(d3 - dm), e4x = __expf(d4 - dm);
    float invd = 1.0f / (e0x + e1x + e2x + e3x + e4x);
    float q0 = e0x * invd, q1 = e1x * invd, q2 = e2x * invd, q3 = e3x * invd, q4 = e4x * invd;

    int col = ((u & 1) << 6) | (u >> 1);
    int base = b * KP + t + u;
    int c1 = (base + 1) * UP + col;
    int c2 = (base + 2) * UP + col;
    int c3 = (base + 3) * UP + col;
    int c4 = (base + 4) * UP + col;
    A[c1 * 8 + 0] = __float2bfloat16(pb * q1);
    A[c2 * 8 + 1] = __float2bfloat16(pb * q2);
    A[c3 * 8 + 2] = __float2bfloat16(pb * q3);
    A[c4 * 8 + 3] = __float2bfloat16(pb * q4);
    if (u + 1 < U) {
      A[c1 * 8 + 4] = __float2bfloat16(py * q0);   // E
      A[c2 * 8 + 5] = __float2bfloat16(py * q1);   // M1
      A[c3 * 8 + 6] = __float2bfloat16(py * q2);   // M2
      A[c4 * 8 + 7] = __float2bfloat16(py * q3);   // M3
      M4p[(base + 5) * UP + col] = __float2bfloat16(py * q4);
    }
  }
}

// ---------------- K2: linear-domain diagonal DP, one wave per batch ----------------
struct OpsP {
  int4 a0, a1;           // 8 bf16 each: {S1..S4, E, M1..M3} for u=2l / u=2l+1
  uint32_t m40, m41;     // M4 weights (bf16 in low 16 bits)
};

DEVINL OpsP load_ops(const int4* __restrict__ pA, const unsigned short* __restrict__ p4,
                     int rowbase, int l) {
  OpsP o;
  int i0 = rowbase + l, i1 = rowbase + 64 + l;
  o.a0 = pA[i0]; o.a1 = pA[i1];
  o.m40 = p4[i0]; o.m41 = p4[i1];
  return o;
}

__global__ void __launch_bounds__(64, 1) k_dp(
    const int4* __restrict__ PA, const unsigned short* __restrict__ PM4,
    const int* __restrict__ act_lens, const int* __restrict__ label_lens,
    float* __restrict__ partial) {
  const int b = blockIdx.x;
  const int l = threadIdx.x;
  const int al = act_lens[b];
  const int ll = label_lens[b];
  const int cb = b * KP * UP;
  const int4* pA = PA + cb;
  const unsigned short* p4 = PM4 + cb;

  const int cll = ((ll & 1) << 6) | (ll >> 1);
  const int4 av = pA[(al + ll) * UP + cll];
  const float sg1 = lo16(av.x), sg2 = hi16(av.x), sg3 = lo16(av.y), sg4 = hi16(av.y);
  const int u0 = 2 * l, u1 = 2 * l + 1;
  const bool isLL0 = (u0 == ll);
  const bool isLL1 = (u1 == ll);
  const int kbase = al + ll - 4;

  // alpha history rings (mantissas at shared per-lane offset o)
  float h01 = 0, h02 = 0, h03 = 0, h04 = 0, h05 = 0; int o0 = 0;
  float h11 = 0, h12 = 0, h13 = 0, h14 = 0, h15 = 0; int o1 = 0;
  float tAm = 0.f; int tAo = -(1 << 28);

  // depth-12 register prefetch ring (~120 VGPRs)
  OpsP q[12];
#pragma unroll
  for (int j = 0; j < 12; ++j) q[j] = load_ops(pA, p4, j * UP, l);

  for (int kb = 0; kb < KD; kb += 12) {
#pragma unroll
    for (int j = 0; j < 12; ++j) {
      const int k = kb + j;
      OpsP cur = q[j];
      q[j] = load_ops(pA, p4, (k + 12) * UP, l);   // row <= 371 < KP

      // unpack bf16 weights
      float s1w = lo16(cur.a0.x), s2w = hi16(cur.a0.x), s3w = lo16(cur.a0.y), s4w = hi16(cur.a0.y);
      float ew0 = lo16(cur.a0.z), m1w = hi16(cur.a0.z), m2w = lo16(cur.a0.w), m3w = hi16(cur.a0.w);
      float w40 = __uint_as_float(cur.m40 << 16);
      float t1w = lo16(cur.a1.x), t2w = hi16(cur.a1.x), t3w = lo16(cur.a1.y), t4w = hi16(cur.a1.y);
      float ew1 = lo16(cur.a1.z), n1w = hi16(cur.a1.z), n2w = lo16(cur.a1.w), n3w = hi16(cur.a1.w);
      float w41 = __uint_as_float(cur.m41 << 16);

      // edge sums from OLD history
      float help0 = fmaf(h01, ew0, fmaf(h02, m1w, fmaf(h03, m2w, fmaf(h04, m3w, h05 * w40))));
      float help1 = fmaf(h11, ew1, fmaf(h12, n1w, fmaf(h13, n2w, fmaf(h14, n3w, h15 * w41))));
      float self0 = fmaf(h01, s1w, fmaf(h02, s2w, fmaf(h03, s3w, h04 * s4w)));
      float self1 = fmaf(h11, t1w, fmaf(h12, t2w, fmaf(h13, t3w, h14 * t4w)));

      // slot0 neighbor (u=2l-1) = slot1 of lane l-1
      float n0 = __shfl_up(help1, 1, 64);
      int on0 = __shfl_up(o1, 1, 64);
      n0 = (l == 0) ? 0.0f : n0;
      on0 = (l == 0) ? o0 : on0;

      // slot0 combine
      int bb0 = (o0 > on0) ? o0 : on0;
      float r0 = ldexpf(self0, o0 - bb0) + ldexpf(n0, on0 - bb0);
      if (k == 0 && l == 0) r0 += 1.0f;              // DP seed at (t=0,u=0)
      float mn0; int en0; renorm(r0, mn0, en0);
      mn0 = ((unsigned)(k - u0) < (unsigned)T && u0 < U) ? mn0 : 0.0f;
      int no0 = bb0 + en0;

      // slot1 combine (neighbor u=2l = same-lane help0 @ o0)
      int bb1 = (o1 > o0) ? o1 : o0;
      float r1 = ldexpf(self1, o1 - bb1) + ldexpf(help0, o0 - bb1);
      float mn1; int en1; renorm(r1, mn1, en1);
      mn1 = ((unsigned)(k - u1) < (unsigned)T && u1 < U) ? mn1 : 0.0f;
      int no1 = bb1 + en1;

      // final-term capture: alpha(al-d,ll) * S_d(al-d,ll) at k = al-d+ll
      unsigned idx = (unsigned)(k - kbase);
      if (idx < 4u) {
        float sg = (idx == 0) ? sg4 : (idx == 1) ? sg3 : (idx == 2) ? sg2 : sg1;
        if (isLL0 | isLL1) {
          float tm = (isLL0 ? mn0 : mn1) * sg;
          int to = isLL0 ? no0 : no1;
          int nb2 = (tAo > to) ? tAo : to;
          tAm = ldexpf(tAm, tAo - nb2) + ldexpf(tm, to - nb2);
          tAo = nb2;
        }
      }

      // push histories (rescale to new offset)
      int dd0 = o0 - no0;
      h05 = ldexpf(h04, dd0); h04 = ldexpf(h03, dd0);
      h03 = ldexpf(h02, dd0); h02 = ldexpf(h01, dd0);
      h01 = mn0; o0 = no0;
      int dd1 = o1 - no1;
      h15 = ldexpf(h14, dd1); h14 = ldexpf(h13, dd1);
      h13 = ldexpf(h12, dd1); h12 = ldexpf(h11, dd1);
      h11 = mn1; o1 = no1;
    }
  }

  if (isLL0 | isLL1) partial[b] = -(log2f(tAm) + (float)tAo) * LN2;
}

// ---------------- K3: batch reduce ----------------
__global__ void k_final(const float* __restrict__ partial, float* __restrict__ out) {
  if (threadIdx.x == 0 && blockIdx.x == 0)
    out[0] = (partial[0] + partial[1] + partial[2] + partial[3]) * 0.25f;
}

extern "C" void kernel_launch(void* const* d_in, const int* in_sizes, int n_in,
                              void* d_out, int out_size, void* d_ws, size_t ws_size,
                              hipStream_t stream) {
  const float* acts = (const float*)d_in[0];
  const int* labels = (const int*)d_in[1];
  const int* act_lens = (const int*)d_in[2];
  const int* label_lens = (const int*)d_in[3];
  float* ws = (float*)d_ws;
  __hip_bfloat16* A = (__hip_bfloat16*)ws;                 // CELLS x 8 bf16
  __hip_bfloat16* M4p = (__hip_bfloat16*)(ws + A_FLOATS);  // CELLS bf16
  float* partial = ws + A_FLOATS + M4_FLOATS;              // [B]
  float* out = (float*)d_out;

  int n4 = (A_FLOATS + M4_FLOATS) / 4;
  k_fill<<<(n4 + 255) / 256, 256, 0, stream>>>(reinterpret_cast<float4*>(ws), n4);
  k_prep<<<BTU / 4, 256, 0, stream>>>(acts, labels, A, M4p);
  k_dp<<<B, 64, 0, stream>>>(reinterpret_cast<const int4*>(A),
                             reinterpret_cast<const unsigned short*>(M4p),
                             act_lens, label_lens, partial);
  k_final<<<1, 64, 0, stream>>>(partial, out);
}

// Round 7
// 159.591 us; speedup vs baseline: 3.0207x; 1.0556x over previous
//
#include <hip/hip_runtime.h>
#include <hip/hip_bf16.h>
#include <cstdint>

#define DEVINL __device__ __forceinline__

namespace {
constexpr int B = 4, T = 256, U = 101, V = 1024;
constexpr int BLANK = 1023;
constexpr float SIGMA = 0.05f;
constexpr int TU = T * U;
constexpr int BTU = B * TU;
constexpr int KP = 376;          // padded diag rows (max touched row = 372)
constexpr int UP = 128;          // padded u stride (A plane)
constexpr int CELLS = B * KP * UP;
constexpr int A_FLOATS = CELLS * 4;   // int4 (8 bf16) per cell
constexpr int M4_FLOATS = CELLS / 2;  // uint32 (2 bf16) per (row, lane)
constexpr float LN2 = 0.6931471805599453f;
}

DEVINL float lo16(uint32_t v) { return __uint_as_float(v << 16); }
DEVINL float hi16(uint32_t v) { return __uint_as_float(v & 0xffff0000u); }
// 2^d as float; out-of-range -> 0 (drops negligible/dead-edge mass only)
DEVINL float mkscale(int d) {
  return ((unsigned)(d + 126) <= 252u) ? ldexpf(1.0f, d) : 0.0f;
}

// ---------------- K0: zero-fill weight planes ----------------
__global__ void __launch_bounds__(256) k_fill(float4* __restrict__ w, int n4) {
  int i = blockIdx.x * 256 + threadIdx.x;
  if (i < n4) w[i] = float4{0.f, 0.f, 0.f, 0.f};
}

// ---------------- K1: softmax rows -> bf16 diagonal weight planes ----
// col(u) = (u&1)*64 + (u>>1): lane l of k_dp owns u=2l (col l) and u=2l+1
// (col 64+l). A[row][col] = 8 bf16 {S1..S4, E, M1..M3}. M4 plane: uint32 per
// (row, lane) = {M4(u=2l) lo, M4(u=2l+1) hi}.
__global__ void __launch_bounds__(256) k_prep(
    const float* __restrict__ acts, const int* __restrict__ labels,
    __hip_bfloat16* __restrict__ A, __hip_bfloat16* __restrict__ M4p) {
  int gwave = (blockIdx.x * 256 + threadIdx.x) >> 6;
  int lane = threadIdx.x & 63;
  if (gwave >= BTU) return;
  int b = gwave / TU;
  int rem = gwave - b * TU;
  int t = rem / U;
  int u = rem - t * U;
  const float* row = acts + (size_t)gwave * (V + 5);

  float x[16];
#pragma unroll
  for (int j = 0; j < 16; ++j) x[j] = row[j * 64 + lane];
  float m = x[0];
#pragma unroll
  for (int j = 1; j < 16; ++j) m = fmaxf(m, x[j]);
#pragma unroll
  for (int off = 32; off >= 1; off >>= 1) m = fmaxf(m, __shfl_xor(m, off, 64));
  float s = 0.f;
#pragma unroll
  for (int j = 0; j < 16; ++j) s += __expf(x[j] - m);
#pragma unroll
  for (int off = 32; off >= 1; off >>= 1) s += __shfl_xor(s, off, 64);

  if (lane == 0) {
    float inv_s = 1.0f / s;
    float pb = __expf(row[BLANK] - m - SIGMA) * inv_s;   // exp(blank_lp)
    int lab = (u < U - 1) ? labels[b * (U - 1) + u] : 0;
    float py = __expf(row[lab] - m - SIGMA) * inv_s;     // exp(y_lp)
    float d0 = row[V], d1 = row[V + 1], d2 = row[V + 2], d3 = row[V + 3], d4 = row[V + 4];
    float dm = fmaxf(fmaxf(fmaxf(d0, d1), fmaxf(d2, d3)), d4);
    float e0x = __expf(d0 - dm), e1x = __expf(d1 - dm), e2x = __expf(d2 - dm),
          e3x = __expf(d3 - dm), e4x = __expf(d4 - dm);
    float invd = 1.0f / (e0x + e1x + e2x + e3x + e4x);
    float q0 = e0x * invd, q1 = e1x * invd, q2 = e2x * invd, q3 = e3x * invd, q4 = e4x * invd;

    int col = ((u & 1) << 6) | (u >> 1);
    int base = b * KP + t + u;
    int c1 = ((base + 1) * UP + col) * 8;
    int c2 = ((base + 2) * UP + col) * 8;
    int c3 = ((base + 3) * UP + col) * 8;
    int c4 = ((base + 4) * UP + col) * 8;
    A[c1 + 0] = __float2bfloat16(pb * q1);
    A[c2 + 1] = __float2bfloat16(pb * q2);
    A[c3 + 2] = __float2bfloat16(pb * q3);
    A[c4 + 3] = __float2bfloat16(pb * q4);
    if (u + 1 < U) {
      A[c1 + 4] = __float2bfloat16(py * q0);   // E
      A[c2 + 5] = __float2bfloat16(py * q1);   // M1
      A[c3 + 6] = __float2bfloat16(py * q2);   // M2
      A[c4 + 7] = __float2bfloat16(py * q3);   // M3
      M4p[((base + 5) * 64 + (u >> 1)) * 2 + (u & 1)] = __float2bfloat16(py * q4);
    }
  }
}

// ---------------- K2: linear-domain diagonal DP, windowed renorm ----------------
struct OpsP { int4 a0, a1; uint32_t m4; };

DEVINL OpsP load_ops(const int4* __restrict__ pA, const uint32_t* __restrict__ pM4,
                     int row, int l) {
  OpsP o;
  int i0 = row * UP + l;
  o.a0 = pA[i0];
  o.a1 = pA[i0 + 64];
  o.m4 = pM4[row * 64 + l];
  return o;
}

__global__ void __launch_bounds__(64, 1) k_dp(
    const int4* __restrict__ PA, const uint32_t* __restrict__ PM4,
    const int* __restrict__ act_lens, const int* __restrict__ label_lens,
    float* __restrict__ partial) {
  const int b = blockIdx.x;
  const int l = threadIdx.x;
  const int al = act_lens[b];
  const int ll = label_lens[b];
  const int4* pA = PA + b * KP * UP;
  const uint32_t* pM4 = PM4 + b * KP * 64;

  const int cll = ((ll & 1) << 6) | (ll >> 1);
  const int4 av = pA[(al + ll) * UP + cll];
  const float sg1 = lo16((uint32_t)av.x), sg2 = hi16((uint32_t)av.x);
  const float sg3 = lo16((uint32_t)av.y), sg4 = hi16((uint32_t)av.y);
  const int u0 = 2 * l, u1 = 2 * l + 1;
  const bool isLL0 = (u0 == ll), isLL1 = (u1 == ll);
  const int kbase = al + ll - 4;

  // history: h[0] = alpha(diag k-1), ..., h[4] = alpha(diag k-5); offsets o0/o1
  float h0[5] = {0, 0, 0, 0, 0}, h1[5] = {0, 0, 0, 0, 0};
  int o0 = 0, o1 = 0;
  if (l == 0) h0[0] = 1.0f;   // alpha(0,0) = 1 (diag 0); loop starts at k=1
  float tAm = 0.0f; int tAo = -100000;

  OpsP q[12];
#pragma unroll
  for (int j = 0; j < 12; ++j) q[j] = load_ops(pA, pM4, j + 1, l);

  for (int blk = 0; blk < 30; ++blk) {
    const int kblk = blk * 12 + 1;
#pragma unroll
    for (int w = 0; w < 3; ++w) {
      // ---- window start: renorm both slots, adopt dead offsets, scales ----
      float pv0 = fmaxf(fmaxf(fmaxf(h0[0], h0[1]), fmaxf(h0[2], h0[3])), h0[4]);
      int eb0 = (int)((__float_as_uint(pv0) >> 23) & 0xffu);
      bool dead0 = (eb0 == 0);
      int d0 = dead0 ? 0 : (127 - eb0);
#pragma unroll
      for (int i = 0; i < 5; ++i) h0[i] = ldexpf(h0[i], d0);
      o0 -= d0;
      float pv1 = fmaxf(fmaxf(fmaxf(h1[0], h1[1]), fmaxf(h1[2], h1[3])), h1[4]);
      int eb1 = (int)((__float_as_uint(pv1) >> 23) & 0xffu);
      bool dead1 = (eb1 == 0);
      int d1 = dead1 ? 0 : (127 - eb1);
#pragma unroll
      for (int i = 0; i < 5; ++i) h1[i] = ldexpf(h1[i], d1);
      o1 -= d1;
      // offset adoption for dead slots (3 rounds: outruns the diagonal front)
#pragma unroll
      for (int r = 0; r < 3; ++r) {
        int on = __shfl_up(o1, 1, 64);
        if (dead0 && l > 0) o0 = on;
        if (dead1) o1 = o0;
      }
      int on0 = __shfl_up(o1, 1, 64);
      float scN = (l == 0) ? 0.0f : mkscale(on0 - o0);  // help1(l-1) -> slot0
      float sc10 = mkscale(o0 - o1);                    // help0 -> slot1 (same lane)

      // ---- 4 diagonals, offsets frozen ----
#pragma unroll
      for (int j = 0; j < 4; ++j) {
        const int rj = w * 4 + j;
        const int k = kblk + rj;
        OpsP cur = q[rj];
        q[rj] = load_ops(pA, pM4, k + 12, l);   // row <= 372 < KP

        uint32_t a0x = (uint32_t)cur.a0.x, a0y = (uint32_t)cur.a0.y;
        uint32_t a0z = (uint32_t)cur.a0.z, a0w = (uint32_t)cur.a0.w;
        uint32_t a1x = (uint32_t)cur.a1.x, a1y = (uint32_t)cur.a1.y;
        uint32_t a1z = (uint32_t)cur.a1.z, a1w = (uint32_t)cur.a1.w;

        float self0 = fmaf(h0[0], lo16(a0x), fmaf(h0[1], hi16(a0x),
                       fmaf(h0[2], lo16(a0y), h0[3] * hi16(a0y))));
        float help0 = fmaf(h0[0], lo16(a0z), fmaf(h0[1], hi16(a0z),
                       fmaf(h0[2], lo16(a0w), fmaf(h0[3], hi16(a0w),
                        h0[4] * lo16(cur.m4)))));
        float self1 = fmaf(h1[0], lo16(a1x), fmaf(h1[1], hi16(a1x),
                       fmaf(h1[2], lo16(a1y), h1[3] * hi16(a1y))));
        float help1 = fmaf(h1[0], lo16(a1z), fmaf(h1[1], hi16(a1z),
                       fmaf(h1[2], lo16(a1w), fmaf(h1[3], hi16(a1w),
                        h1[4] * hi16(cur.m4)))));

        float n0 = __shfl_up(help1, 1, 64);     // mass into u0 from lane l-1
        float r0 = fmaf(n0, scN, self0);
        float r1 = fmaf(help0, sc10, self1);

        float r0g = ((unsigned)(k - u0) < (unsigned)T) ? r0 : 0.0f;
        float r1g = ((unsigned)(k - u1) < (unsigned)T) ? r1 : 0.0f;

        // final-term capture: alpha(al-d,ll) * S_d(al-d,ll) at k = al-d+ll
        unsigned idx = (unsigned)(k - kbase);
        if (idx < 4u) {
          if (isLL0 | isLL1) {
            float sg = (idx == 0) ? sg4 : (idx == 1) ? sg3 : (idx == 2) ? sg2 : sg1;
            float tm = (isLL0 ? r0g : r1g) * sg;
            int to = isLL0 ? o0 : o1;
            int nb2 = (tAo > to) ? tAo : to;
            tAm = ldexpf(tAm, tAo - nb2) + ldexpf(tm, to - nb2);
            tAo = nb2;
          }
        }

        // history shift: pure register renaming (offsets frozen in window)
        h0[4] = h0[3]; h0[3] = h0[2]; h0[2] = h0[1]; h0[1] = h0[0]; h0[0] = r0g;
        h1[4] = h1[3]; h1[3] = h1[2]; h1[2] = h1[1]; h1[1] = h1[0]; h1[0] = r1g;
      }
    }
  }

  if (isLL0 | isLL1) partial[b] = -(log2f(tAm) + (float)tAo) * LN2;
}

// ---------------- K3: batch reduce ----------------
__global__ void k_final(const float* __restrict__ partial, float* __restrict__ out) {
  if (threadIdx.x == 0 && blockIdx.x == 0)
    out[0] = (partial[0] + partial[1] + partial[2] + partial[3]) * 0.25f;
}

extern "C" void kernel_launch(void* const* d_in, const int* in_sizes, int n_in,
                              void* d_out, int out_size, void* d_ws, size_t ws_size,
                              hipStream_t stream) {
  const float* acts = (const float*)d_in[0];
  const int* labels = (const int*)d_in[1];
  const int* act_lens = (const int*)d_in[2];
  const int* label_lens = (const int*)d_in[3];
  float* ws = (float*)d_ws;
  __hip_bfloat16* A = (__hip_bfloat16*)ws;                 // CELLS x 8 bf16
  __hip_bfloat16* M4p = (__hip_bfloat16*)(ws + A_FLOATS);  // CELLS/2 x uint32
  float* partial = ws + A_FLOATS + M4_FLOATS;              // [B]
  float* out = (float*)d_out;

  int n4 = (A_FLOATS + M4_FLOATS) / 4;
  k_fill<<<(n4 + 255) / 256, 256, 0, stream>>>(reinterpret_cast<float4*>(ws), n4);
  k_prep<<<BTU / 4, 256, 0, stream>>>(acts, labels, A, M4p);
  k_dp<<<B, 64, 0, stream>>>(reinterpret_cast<const int4*>(A),
                             reinterpret_cast<const uint32_t*>(M4p),
                             act_lens, label_lens, partial);
  k_final<<<1, 64, 0, stream>>>(partial, out);
}